// Round 5
// baseline (1131.773 us; speedup 1.0000x reference)
//
#include <hip/hip_runtime.h>
#include <hip/hip_fp16.h>

#define N_NODES 500000
#define N_EDGES 5000000
#define D 16

#define BSH 9                       // 512 nodes per bucket
#define BN (1 << BSH)
#define NB ((N_NODES + BN - 1) >> BSH)      // 977
#define SRC_BITS 19
#define SRC_MASK ((1u << SRC_BITS) - 1)
#define BIN_CHUNK 8192
#define NBIN_BLOCKS ((N_EDGES + BIN_CHUNK - 1) / BIN_CHUNK)  // 611

// ---------------------------------------------------------------------------
// 0) Cast x (f32) -> x16 (f16): halves gather table to 16 MB.
// ---------------------------------------------------------------------------
__global__ __launch_bounds__(256) void cast_kernel(
    const float* __restrict__ x, __half2* __restrict__ x16) {
    int i = blockIdx.x * 256 + threadIdx.x;
    if (i < N_NODES * 8) {
        float2 v = ((const float2*)x)[i];
        x16[i] = __float22half2_rn(v);
    }
}

// ---------------------------------------------------------------------------
// 1) Per-bucket edge counts (LDS histogram, one flush per block).
// ---------------------------------------------------------------------------
__global__ __launch_bounds__(256) void hist_kernel(
    const int* __restrict__ edge_index, int* __restrict__ cnt) {
    __shared__ int h[NB];
    for (int i = threadIdx.x; i < NB; i += 256) h[i] = 0;
    __syncthreads();
    int stride = gridDim.x * 256;
    for (int e = blockIdx.x * 256 + threadIdx.x; e < N_EDGES; e += stride)
        atomicAdd(&h[edge_index[N_EDGES + e] >> BSH], 1);
    __syncthreads();
    for (int i = threadIdx.x; i < NB; i += 256)
        if (h[i]) atomicAdd(&cnt[i], h[i]);
}

// ---------------------------------------------------------------------------
// 2) Exclusive scan of NB counts (single block, 4 counters/thread).
//    base[b] = start of bucket b in binned[]; cursor = running copy.
// ---------------------------------------------------------------------------
__global__ __launch_bounds__(256) void scan_kernel(
    const int* __restrict__ cnt, int* __restrict__ base, int* __restrict__ cursor) {
    __shared__ int sums[256];
    int t = threadIdx.x;
    int v[4]; int ts = 0;
    #pragma unroll
    for (int j = 0; j < 4; ++j) {
        int i = t * 4 + j;
        v[j] = (i < NB) ? cnt[i] : 0;
        ts += v[j];
    }
    sums[t] = ts;
    __syncthreads();
    for (int off = 1; off < 256; off <<= 1) {
        int val = (t >= off) ? sums[t - off] : 0;
        __syncthreads();
        if (t >= off) sums[t] += val;
        __syncthreads();
    }
    int p = sums[t] - ts;
    #pragma unroll
    for (int j = 0; j < 4; ++j) {
        int i = t * 4 + j;
        if (i < NB) { base[i] = p; cursor[i] = p; }
        p += v[j];
    }
    if (t == 255) base[NB] = p;   // = N_EDGES
}

// ---------------------------------------------------------------------------
// 3) LDS-staged binning: edges -> binned[], grouped by dst-bucket, with
//    coalesced run writes. Entry = src (19b) | dst_local (9b) << 19.
// ---------------------------------------------------------------------------
__global__ __launch_bounds__(256) void bin_kernel(
    const int* __restrict__ edge_index, int* __restrict__ cursor,
    unsigned int* __restrict__ binned) {
    __shared__ unsigned int buf[BIN_CHUNK];        // 32 KB
    __shared__ unsigned short bufB[BIN_CHUNK];     // 16 KB
    __shared__ int hist[NB];                       // counts, then local cursor
    __shared__ int lofs[NB];
    __shared__ int gofs[NB];
    __shared__ int sums[256];

    int t = threadIdx.x;
    int start = blockIdx.x * BIN_CHUNK;
    int count = min(BIN_CHUNK, N_EDGES - start);

    for (int i = t; i < NB; i += 256) hist[i] = 0;
    __syncthreads();
    for (int k = t; k < count; k += 256)
        atomicAdd(&hist[edge_index[N_EDGES + start + k] >> BSH], 1);
    __syncthreads();

    // exclusive scan of hist -> lofs
    int v[4]; int ts = 0;
    #pragma unroll
    for (int j = 0; j < 4; ++j) {
        int i = t * 4 + j;
        v[j] = (i < NB) ? hist[i] : 0;
        ts += v[j];
    }
    sums[t] = ts;
    __syncthreads();
    for (int off = 1; off < 256; off <<= 1) {
        int val = (t >= off) ? sums[t - off] : 0;
        __syncthreads();
        if (t >= off) sums[t] += val;
        __syncthreads();
    }
    int p = sums[t] - ts;
    #pragma unroll
    for (int j = 0; j < 4; ++j) {
        int i = t * 4 + j;
        if (i < NB) lofs[i] = p;
        p += v[j];
    }
    __syncthreads();

    // reserve global ranges
    for (int i = t; i < NB; i += 256) {
        int c = hist[i];
        gofs[i] = c ? atomicAdd(&cursor[i], c) : 0;
    }
    __syncthreads();
    for (int i = t; i < NB; i += 256) hist[i] = lofs[i];   // reuse as local cursor
    __syncthreads();

    // place edges into LDS buffer grouped by bucket
    for (int k = t; k < count; k += 256) {
        int s = edge_index[start + k];
        int d = edge_index[N_EDGES + start + k];
        int b = d >> BSH;
        int pos = atomicAdd(&hist[b], 1);
        buf[pos] = (unsigned int)s | ((unsigned int)(d & (BN - 1)) << SRC_BITS);
        bufB[pos] = (unsigned short)b;
    }
    __syncthreads();

    // coalesced write-out per bucket run
    for (int i = t; i < count; i += 256) {
        int b = bufB[i];
        binned[gofs[b] + (i - lofs[b])] = buf[i];
    }
}

// ---------------------------------------------------------------------------
// 4) Fused layer 1: LDS f32 accumulate of x16[src] per dst-bucket, then
//    h1 = f16(relu(agg @ WrelT + b + x @ WrootT)). One block per bucket.
// ---------------------------------------------------------------------------
__global__ __launch_bounds__(512) void layer1_kernel(
    const __half* __restrict__ x16,
    const unsigned int* __restrict__ binned,
    const int* __restrict__ base,
    const float* __restrict__ w_rel, const float* __restrict__ b_rel,
    const float* __restrict__ w_root,
    __half* __restrict__ h1out) {
    __shared__ float agg[BN * D];                  // 32 KB
    __shared__ float sWrelT[D * D], sWrootT[D * D], sB[D];
    int t = threadIdx.x;
    if (t < 256) {
        int r = t >> 4, c = t & 15;
        sWrelT[c * D + r] = w_rel[r * D + c];
        sWrootT[c * D + r] = w_root[r * D + c];
        if (t < D) sB[t] = b_rel[t];
    }
    for (int i = t; i < BN * D; i += 512) agg[i] = 0.f;
    __syncthreads();

    int bkt = blockIdx.x;
    int e0 = base[bkt], e1 = base[bkt + 1];
    int q = t & 3;
    #pragma unroll 2
    for (int idx = e0 + (t >> 2); idx < e1; idx += 128) {
        unsigned int entry = binned[idx];
        int src = entry & SRC_MASK;
        int dl = entry >> SRC_BITS;
        float2 raw = ((const float2*)(x16 + (long)src * D))[q];   // 8B of 32B row
        float2 fa = __half22float2(((__half2*)&raw)[0]);
        float2 fb = __half22float2(((__half2*)&raw)[1]);
        float* ap = &agg[dl * D + q * 4];
        atomicAdd(ap + 0, fa.x);
        atomicAdd(ap + 1, fa.y);
        atomicAdd(ap + 2, fb.x);
        atomicAdd(ap + 3, fb.y);
    }
    __syncthreads();

    int d = t & 15;
    for (int n = (t >> 4); n < BN; n += 32) {
        int node = (bkt << BSH) + n;
        if (node >= N_NODES) continue;
        const float2* xr = (const float2*)(x16 + (long)node * D);
        float xk[D];
        #pragma unroll
        for (int qq = 0; qq < 4; ++qq) {
            float2 raw = xr[qq];
            float2 fa = __half22float2(((__half2*)&raw)[0]);
            float2 fb = __half22float2(((__half2*)&raw)[1]);
            xk[qq * 4 + 0] = fa.x; xk[qq * 4 + 1] = fa.y;
            xk[qq * 4 + 2] = fb.x; xk[qq * 4 + 3] = fb.y;
        }
        float acc = sB[d];
        #pragma unroll
        for (int k = 0; k < D; ++k)
            acc += agg[n * D + k] * sWrelT[k * D + d] + xk[k] * sWrootT[k * D + d];
        h1out[(long)node * D + d] = __float2half(acc > 0.f ? acc : 0.f);
    }
}

// ---------------------------------------------------------------------------
// 5) Fused layer 2 + head: agg from h1; h2 = relu(conv2); out = fc2(relu(fc1(h2)))
// ---------------------------------------------------------------------------
__global__ __launch_bounds__(512) void layer2_kernel(
    const __half* __restrict__ h1,
    const unsigned int* __restrict__ binned,
    const int* __restrict__ base,
    const float* __restrict__ w_rel, const float* __restrict__ b_rel,
    const float* __restrict__ w_root,
    const float* __restrict__ fc1_w, const float* __restrict__ fc1_b,
    const float* __restrict__ fc2_w, const float* __restrict__ fc2_b,
    float* __restrict__ out) {
    __shared__ float agg[BN * D];
    __shared__ float sWrelT[D * D], sWrootT[D * D], sB[D];
    __shared__ float sF1w[8 * D], sF1b[8], sF2w[2 * 8], sF2b[2];
    int t = threadIdx.x;
    if (t < 256) {
        int r = t >> 4, c = t & 15;
        sWrelT[c * D + r] = w_rel[r * D + c];
        sWrootT[c * D + r] = w_root[r * D + c];
        if (t < D) sB[t] = b_rel[t];
        if (t < 8 * D) sF1w[t] = fc1_w[t];
        if (t < 8) sF1b[t] = fc1_b[t];
        if (t < 16) sF2w[t] = fc2_w[t];
        if (t < 2) sF2b[t] = fc2_b[t];
    }
    for (int i = t; i < BN * D; i += 512) agg[i] = 0.f;
    __syncthreads();

    int bkt = blockIdx.x;
    int e0 = base[bkt], e1 = base[bkt + 1];
    int q = t & 3;
    #pragma unroll 2
    for (int idx = e0 + (t >> 2); idx < e1; idx += 128) {
        unsigned int entry = binned[idx];
        int src = entry & SRC_MASK;
        int dl = entry >> SRC_BITS;
        float2 raw = ((const float2*)(h1 + (long)src * D))[q];
        float2 fa = __half22float2(((__half2*)&raw)[0]);
        float2 fb = __half22float2(((__half2*)&raw)[1]);
        float* ap = &agg[dl * D + q * 4];
        atomicAdd(ap + 0, fa.x);
        atomicAdd(ap + 1, fa.y);
        atomicAdd(ap + 2, fb.x);
        atomicAdd(ap + 3, fb.y);
    }
    __syncthreads();

    // h2 = relu(conv2), overwrite agg row in place (each lane writes its own slot)
    int d = t & 15;
    for (int n = (t >> 4); n < BN; n += 32) {
        int node = (bkt << BSH) + n;
        if (node >= N_NODES) continue;
        const float2* xr = (const float2*)(h1 + (long)node * D);
        float xk[D];
        #pragma unroll
        for (int qq = 0; qq < 4; ++qq) {
            float2 raw = xr[qq];
            float2 fa = __half22float2(((__half2*)&raw)[0]);
            float2 fb = __half22float2(((__half2*)&raw)[1]);
            xk[qq * 4 + 0] = fa.x; xk[qq * 4 + 1] = fa.y;
            xk[qq * 4 + 2] = fb.x; xk[qq * 4 + 3] = fb.y;
        }
        float acc = sB[d];
        #pragma unroll
        for (int k = 0; k < D; ++k)
            acc += agg[n * D + k] * sWrelT[k * D + d] + xk[k] * sWrootT[k * D + d];
        agg[n * D + d] = acc > 0.f ? acc : 0.f;   // reads (above) precede write
    }
    __syncthreads();

    // head: 2 output dims per node; task = node*2 + dd
    for (int it = 0; it < 2; ++it) {
        int task = t + it * 512;
        int n = task >> 1, dd = task & 1;
        int node = (bkt << BSH) + n;
        if (node >= N_NODES) continue;
        float h3[8];
        #pragma unroll
        for (int j = 0; j < 8; ++j) {
            float acc = sF1b[j];
            #pragma unroll
            for (int k = 0; k < D; ++k) acc += agg[n * D + k] * sF1w[j * D + k];
            h3[j] = acc > 0.f ? acc : 0.f;
        }
        float o = sF2b[dd];
        #pragma unroll
        for (int j = 0; j < 8; ++j) o += h3[j] * sF2w[dd * 8 + j];
        out[(long)node * 2 + dd] = o;
    }
}

extern "C" void kernel_launch(void* const* d_in, const int* in_sizes, int n_in,
                              void* d_out, int out_size, void* d_ws, size_t ws_size,
                              hipStream_t stream) {
    const float* x          = (const float*)d_in[0];
    const int*   edge_index = (const int*)d_in[1];
    const float* c1_wrel    = (const float*)d_in[2];
    const float* c1_brel    = (const float*)d_in[3];
    const float* c1_wroot   = (const float*)d_in[4];
    const float* c2_wrel    = (const float*)d_in[5];
    const float* c2_brel    = (const float*)d_in[6];
    const float* c2_wroot   = (const float*)d_in[7];
    const float* fc1_w      = (const float*)d_in[8];
    const float* fc1_b      = (const float*)d_in[9];
    const float* fc2_w      = (const float*)d_in[10];
    const float* fc2_b      = (const float*)d_in[11];
    float* out = (float*)d_out;

    // Workspace (4B units): x16 [N*8], h1 [N*8], binned [E], cnt/base/cursor
    __half2* x16h2 = (__half2*)d_ws;
    __half*  x16   = (__half*)d_ws;
    __half*  h1    = (__half*)((char*)d_ws + (size_t)N_NODES * D * 2);
    unsigned int* binned = (unsigned int*)((char*)d_ws + 2 * (size_t)N_NODES * D * 2);
    int* cnt    = (int*)(binned + N_EDGES);
    int* base   = cnt + NB;
    int* cursor = base + (NB + 1);

    hipMemsetAsync(cnt, 0, NB * sizeof(int), stream);
    cast_kernel<<<(N_NODES * 8 + 255) / 256, 256, 0, stream>>>(x, x16h2);
    hist_kernel<<<1024, 256, 0, stream>>>(edge_index, cnt);
    scan_kernel<<<1, 256, 0, stream>>>(cnt, base, cursor);
    bin_kernel<<<NBIN_BLOCKS, 256, 0, stream>>>(edge_index, cursor, binned);

    layer1_kernel<<<NB, 512, 0, stream>>>(
        x16, binned, base, c1_wrel, c1_brel, c1_wroot, h1);
    layer2_kernel<<<NB, 512, 0, stream>>>(
        h1, binned, base, c2_wrel, c2_brel, c2_wroot,
        fc1_w, fc1_b, fc2_w, fc2_b, out);
}

// Round 6
// 786.079 us; speedup vs baseline: 1.4398x; 1.4398x over previous
//
#include <hip/hip_runtime.h>
#include <hip/hip_fp16.h>

#define N_NODES 500000
#define N_EDGES 5000000
#define D 16

#define BSH 9                              // 512 nodes per src-bucket
#define BN (1 << BSH)
#define NB ((N_NODES + BN - 1) >> BSH)     // 977
#define BIN_CHUNK 8192
#define NBIN_BLOCKS ((N_EDGES + BIN_CHUNK - 1) / BIN_CHUNK)  // 611

// ---------------------------------------------------------------------------
// 0) Cast x (f32) -> x16 (f16) table.
// ---------------------------------------------------------------------------
__global__ __launch_bounds__(256) void cast_kernel(
    const float* __restrict__ x, __half2* __restrict__ x16) {
    int i = blockIdx.x * 256 + threadIdx.x;
    if (i < N_NODES * 8) {
        float2 v = ((const float2*)x)[i];
        x16[i] = __float22half2_rn(v);
    }
}

// ---------------------------------------------------------------------------
// 1) Per-SRC-bucket edge counts (LDS histogram).
// ---------------------------------------------------------------------------
__global__ __launch_bounds__(256) void hist_kernel(
    const int* __restrict__ edge_index, int* __restrict__ cnt) {
    __shared__ int h[NB];
    for (int i = threadIdx.x; i < NB; i += 256) h[i] = 0;
    __syncthreads();
    int stride = gridDim.x * 256;
    for (int e = blockIdx.x * 256 + threadIdx.x; e < N_EDGES; e += stride)
        atomicAdd(&h[edge_index[e] >> BSH], 1);   // src row
    __syncthreads();
    for (int i = threadIdx.x; i < NB; i += 256)
        if (h[i]) atomicAdd(&cnt[i], h[i]);
}

// ---------------------------------------------------------------------------
// 2) Exclusive scan of NB counts (single block).
// ---------------------------------------------------------------------------
__global__ __launch_bounds__(256) void scan_kernel(
    const int* __restrict__ cnt, int* __restrict__ base, int* __restrict__ cursor) {
    __shared__ int sums[256];
    int t = threadIdx.x;
    int v[4]; int ts = 0;
    #pragma unroll
    for (int j = 0; j < 4; ++j) {
        int i = t * 4 + j;
        v[j] = (i < NB) ? cnt[i] : 0;
        ts += v[j];
    }
    sums[t] = ts;
    __syncthreads();
    for (int off = 1; off < 256; off <<= 1) {
        int val = (t >= off) ? sums[t - off] : 0;
        __syncthreads();
        if (t >= off) sums[t] += val;
        __syncthreads();
    }
    int p = sums[t] - ts;
    #pragma unroll
    for (int j = 0; j < 4; ++j) {
        int i = t * 4 + j;
        if (i < NB) { base[i] = p; cursor[i] = p; }
        p += v[j];
    }
    if (t == 255) base[NB] = p;   // = N_EDGES
}

// ---------------------------------------------------------------------------
// 3) LDS-staged binning by SRC bucket, coalesced run write-out.
//    Entry = (dst 19b) << 9 | src_local (9b).
// ---------------------------------------------------------------------------
__global__ __launch_bounds__(256) void bin_kernel(
    const int* __restrict__ edge_index, int* __restrict__ cursor,
    unsigned int* __restrict__ binned) {
    __shared__ unsigned int buf[BIN_CHUNK];        // 32 KB
    __shared__ unsigned short bufB[BIN_CHUNK];     // 16 KB
    __shared__ int hist[NB];
    __shared__ int lofs[NB];
    __shared__ int gofs[NB];
    __shared__ int sums[256];

    int t = threadIdx.x;
    int start = blockIdx.x * BIN_CHUNK;
    int count = min(BIN_CHUNK, N_EDGES - start);

    for (int i = t; i < NB; i += 256) hist[i] = 0;
    __syncthreads();
    for (int k = t; k < count; k += 256)
        atomicAdd(&hist[edge_index[start + k] >> BSH], 1);
    __syncthreads();

    int v[4]; int ts = 0;
    #pragma unroll
    for (int j = 0; j < 4; ++j) {
        int i = t * 4 + j;
        v[j] = (i < NB) ? hist[i] : 0;
        ts += v[j];
    }
    sums[t] = ts;
    __syncthreads();
    for (int off = 1; off < 256; off <<= 1) {
        int val = (t >= off) ? sums[t - off] : 0;
        __syncthreads();
        if (t >= off) sums[t] += val;
        __syncthreads();
    }
    int p = sums[t] - ts;
    #pragma unroll
    for (int j = 0; j < 4; ++j) {
        int i = t * 4 + j;
        if (i < NB) lofs[i] = p;
        p += v[j];
    }
    __syncthreads();

    for (int i = t; i < NB; i += 256) {
        int c = hist[i];
        gofs[i] = c ? atomicAdd(&cursor[i], c) : 0;
    }
    __syncthreads();
    for (int i = t; i < NB; i += 256) hist[i] = lofs[i];
    __syncthreads();

    for (int k = t; k < count; k += 256) {
        int s = edge_index[start + k];
        int d = edge_index[N_EDGES + start + k];
        int b = s >> BSH;
        int pos = atomicAdd(&hist[b], 1);
        buf[pos] = ((unsigned int)d << BSH) | (unsigned int)(s & (BN - 1));
        bufB[pos] = (unsigned short)b;
    }
    __syncthreads();

    for (int i = t; i < count; i += 256) {
        int b = bufB[i];
        binned[gofs[b] + (i - lofs[b])] = buf[i];
    }
}

// ---------------------------------------------------------------------------
// 4) Scatter (both layers): block owns one SRC bucket; stage its 512 f16
//    rows in LDS (16 KB, each fetched from L2 exactly once); stream edges,
//    fire packed-f16 atomics at agg[dst]. 8 lanes per edge, fire-and-forget.
// ---------------------------------------------------------------------------
__global__ __launch_bounds__(256) void scatter_kernel(
    const __half* __restrict__ feat16,           // [N][16]
    const unsigned int* __restrict__ binned,
    const int* __restrict__ base,
    __half2* __restrict__ agg) {                 // [N][8]
    __shared__ unsigned int srow[BN * 8];        // 16 KB
    int t = threadIdx.x;
    int bkt = blockIdx.x;
    int n0 = bkt << BSH;
    int nrows = min(BN, N_NODES - n0);
    const unsigned int* gsrc = (const unsigned int*)(feat16 + (long)n0 * D);
    for (int i = t; i < nrows * 8; i += 256) srow[i] = gsrc[i];
    __syncthreads();

    int e0 = base[bkt], e1 = base[bkt + 1];
    int lane8 = t & 7;
    for (int idx = e0 + (t >> 3); idx < e1; idx += 32) {
        unsigned int entry = binned[idx];
        int sl = (int)(entry & (BN - 1));
        int dst = (int)(entry >> BSH);
        unsigned int payload = srow[sl * 8 + lane8];
        unsafeAtomicAdd(&agg[(long)dst * 8 + lane8], *(__half2*)&payload);
    }
}

// ---------------------------------------------------------------------------
// 5) Node layer 1: h1 = f16(relu(agg @ WrelT + b + x @ WrootT))  (x read f32)
// ---------------------------------------------------------------------------
__global__ __launch_bounds__(256) void node1_kernel(
    const float* __restrict__ x,
    const __half2* __restrict__ agg,
    const float* __restrict__ w_rel,
    const float* __restrict__ b_rel,
    const float* __restrict__ w_root,
    __half2* __restrict__ h1) {
    __shared__ float sWrel[D * D];
    __shared__ float sWroot[D * D];
    __shared__ float sB[D];
    for (int i = threadIdx.x; i < D * D; i += blockDim.x) {
        sWrel[i] = w_rel[i];
        sWroot[i] = w_root[i];
    }
    if (threadIdx.x < D) sB[threadIdx.x] = b_rel[threadIdx.x];
    __syncthreads();

    int i = blockIdx.x * blockDim.x + threadIdx.x;
    if (i >= N_NODES) return;

    float a[D], xi[D];
    {
        __half2 hrow[8];
        const float4* ap = (const float4*)(agg + (long)i * 8);
        *(float4*)&hrow[0] = ap[0];
        *(float4*)&hrow[4] = ap[1];
        #pragma unroll
        for (int q = 0; q < 8; ++q) {
            float2 f = __half22float2(hrow[q]);
            a[2 * q] = f.x; a[2 * q + 1] = f.y;
        }
        const float4* xp = (const float4*)(x + (long)i * D);
        #pragma unroll
        for (int q = 0; q < 4; ++q) {
            float4 xv = xp[q];
            xi[q * 4 + 0] = xv.x; xi[q * 4 + 1] = xv.y;
            xi[q * 4 + 2] = xv.z; xi[q * 4 + 3] = xv.w;
        }
    }

    __half2 hout[8];
    #pragma unroll
    for (int q = 0; q < 8; ++q) {
        float o0, o1;
        #pragma unroll
        for (int r = 0; r < 2; ++r) {
            int dd = 2 * q + r;
            float acc = sB[dd];
            #pragma unroll
            for (int k = 0; k < D; ++k)
                acc += a[k] * sWrel[dd * D + k] + xi[k] * sWroot[dd * D + k];
            acc = acc > 0.f ? acc : 0.f;
            if (r == 0) o0 = acc; else o1 = acc;
        }
        hout[q] = __float22half2_rn(make_float2(o0, o1));
    }
    float4* hp = (float4*)(h1 + (long)i * 8);
    hp[0] = *(float4*)&hout[0];
    hp[1] = *(float4*)&hout[4];
}

// ---------------------------------------------------------------------------
// 6) Node layer 2 + head.
// ---------------------------------------------------------------------------
__global__ __launch_bounds__(256) void node2_kernel(
    const __half2* __restrict__ h1,
    const __half2* __restrict__ agg,
    const float* __restrict__ w_rel,
    const float* __restrict__ b_rel,
    const float* __restrict__ w_root,
    const float* __restrict__ fc1_w,
    const float* __restrict__ fc1_b,
    const float* __restrict__ fc2_w,
    const float* __restrict__ fc2_b,
    float* __restrict__ out) {
    __shared__ float sWrel[D * D];
    __shared__ float sWroot[D * D];
    __shared__ float sB[D];
    __shared__ float sF1w[8 * D];
    __shared__ float sF1b[8];
    __shared__ float sF2w[2 * 8];
    __shared__ float sF2b[2];
    for (int i = threadIdx.x; i < D * D; i += blockDim.x) {
        sWrel[i] = w_rel[i];
        sWroot[i] = w_root[i];
    }
    if (threadIdx.x < D) sB[threadIdx.x] = b_rel[threadIdx.x];
    if (threadIdx.x < 8 * D) sF1w[threadIdx.x] = fc1_w[threadIdx.x];
    if (threadIdx.x < 8) sF1b[threadIdx.x] = fc1_b[threadIdx.x];
    if (threadIdx.x < 16) sF2w[threadIdx.x] = fc2_w[threadIdx.x];
    if (threadIdx.x < 2) sF2b[threadIdx.x] = fc2_b[threadIdx.x];
    __syncthreads();

    int i = blockIdx.x * blockDim.x + threadIdx.x;
    if (i >= N_NODES) return;

    float a[D], xi[D];
    {
        __half2 hrow[8];
        const float4* ap = (const float4*)(agg + (long)i * 8);
        *(float4*)&hrow[0] = ap[0];
        *(float4*)&hrow[4] = ap[1];
        #pragma unroll
        for (int q = 0; q < 8; ++q) {
            float2 f = __half22float2(hrow[q]);
            a[2 * q] = f.x; a[2 * q + 1] = f.y;
        }
        const float4* xp = (const float4*)(h1 + (long)i * 8);
        *(float4*)&hrow[0] = xp[0];
        *(float4*)&hrow[4] = xp[1];
        #pragma unroll
        for (int q = 0; q < 8; ++q) {
            float2 f = __half22float2(hrow[q]);
            xi[2 * q] = f.x; xi[2 * q + 1] = f.y;
        }
    }

    float h2[D];
    #pragma unroll
    for (int dd = 0; dd < D; ++dd) {
        float acc = sB[dd];
        #pragma unroll
        for (int k = 0; k < D; ++k)
            acc += a[k] * sWrel[dd * D + k] + xi[k] * sWroot[dd * D + k];
        h2[dd] = acc > 0.f ? acc : 0.f;
    }

    float h3[8];
    #pragma unroll
    for (int j = 0; j < 8; ++j) {
        float acc = sF1b[j];
        #pragma unroll
        for (int k = 0; k < D; ++k) acc += h2[k] * sF1w[j * D + k];
        h3[j] = acc > 0.f ? acc : 0.f;
    }

    float2 o;
    {
        float acc0 = sF2b[0], acc1 = sF2b[1];
        #pragma unroll
        for (int j = 0; j < 8; ++j) {
            acc0 += h3[j] * sF2w[0 * 8 + j];
            acc1 += h3[j] * sF2w[1 * 8 + j];
        }
        o.x = acc0;
        o.y = acc1;
    }
    ((float2*)out)[i] = o;
}

extern "C" void kernel_launch(void* const* d_in, const int* in_sizes, int n_in,
                              void* d_out, int out_size, void* d_ws, size_t ws_size,
                              hipStream_t stream) {
    const float* x          = (const float*)d_in[0];
    const int*   edge_index = (const int*)d_in[1];
    const float* c1_wrel    = (const float*)d_in[2];
    const float* c1_brel    = (const float*)d_in[3];
    const float* c1_wroot   = (const float*)d_in[4];
    const float* c2_wrel    = (const float*)d_in[5];
    const float* c2_brel    = (const float*)d_in[6];
    const float* c2_wroot   = (const float*)d_in[7];
    const float* fc1_w      = (const float*)d_in[8];
    const float* fc1_b      = (const float*)d_in[9];
    const float* fc2_w      = (const float*)d_in[10];
    const float* fc2_b      = (const float*)d_in[11];
    float* out = (float*)d_out;

    // Workspace: agg 16 MB | h1 16 MB | x16 16 MB | binned 20 MB | cnt/base/cursor
    __half2* agg = (__half2*)d_ws;
    __half2* h1  = agg + (size_t)N_NODES * 8;
    __half2* x16 = h1 + (size_t)N_NODES * 8;
    unsigned int* binned = (unsigned int*)(x16 + (size_t)N_NODES * 8);
    int* cnt    = (int*)(binned + N_EDGES);
    int* base   = cnt + NB;
    int* cursor = base + (NB + 1);

    size_t agg_bytes = (size_t)N_NODES * 8 * sizeof(__half2);
    const int BLK = 256;
    int node_blocks = (N_NODES + BLK - 1) / BLK;

    // --- Build src-binned edge list (amortized over both layers) ---
    hipMemsetAsync(cnt, 0, NB * sizeof(int), stream);
    cast_kernel<<<(N_NODES * 8 + 255) / 256, 256, 0, stream>>>(x, x16);
    hist_kernel<<<1024, 256, 0, stream>>>(edge_index, cnt);
    scan_kernel<<<1, 256, 0, stream>>>(cnt, base, cursor);
    bin_kernel<<<NBIN_BLOCKS, 256, 0, stream>>>(edge_index, cursor, binned);

    // --- Layer 1 ---
    hipMemsetAsync(agg, 0, agg_bytes, stream);
    scatter_kernel<<<NB, BLK, 0, stream>>>((const __half*)x16, binned, base, agg);
    node1_kernel<<<node_blocks, BLK, 0, stream>>>(x, agg, c1_wrel, c1_brel, c1_wroot, h1);

    // --- Layer 2 + head ---
    hipMemsetAsync(agg, 0, agg_bytes, stream);
    scatter_kernel<<<NB, BLK, 0, stream>>>((const __half*)h1, binned, base, agg);
    node2_kernel<<<node_blocks, BLK, 0, stream>>>(h1, agg, c2_wrel, c2_brel, c2_wroot,
                                                  fc1_w, fc1_b, fc2_w, fc2_b, out);
}